// Round 3
// baseline (139.745 us; speedup 1.0000x reference)
//
#include <hip/hip_runtime.h>
#include <hip/hip_bf16.h>
#include <hip/hip_cooperative_groups.h>

namespace cg = cooperative_groups;

#define DDIM 128
#define NBLK 256
#define NTHR 1024
#define MAX_TAB32 25088   // 50176 bf16 entries = 100352 B LDS

typedef float vf4 __attribute__((ext_vector_type(4)));
typedef int   vi4 __attribute__((ext_vector_type(4)));

__device__ __forceinline__ float bf16_to_f32(unsigned short u) {
    return __uint_as_float(((unsigned int)u) << 16);
}

// Batched vi4 copy: 4 loads in flight, then 4 LDS stores. Transient
// register cost = 16 VGPRs; never held across a barrier.
__device__ __forceinline__ void stage_table(
    vi4* __restrict__ tab128, unsigned int* __restrict__ tab32,
    const vi4* __restrict__ g128, const unsigned int* __restrict__ g32,
    int n128, int n32, int tid)
{
    int i = tid;
    for (; i + 3 * NTHR < n128; i += 4 * NTHR) {
        const vi4 a = g128[i];
        const vi4 b = g128[i +     NTHR];
        const vi4 c = g128[i + 2 * NTHR];
        const vi4 d = g128[i + 3 * NTHR];
        tab128[i          ] = a;
        tab128[i +     NTHR] = b;
        tab128[i + 2 * NTHR] = c;
        tab128[i + 3 * NTHR] = d;
    }
    for (; i < n128; i += NTHR) tab128[i] = g128[i];
    for (int j = (n128 << 2) + tid; j < n32; j += NTHR) tab32[j] = g32[j];
}

// Fused: phase A projects nodes (grid-stride), grid-wide sync, phase B
// scores edges from LDS-resident bf16 tables (stage xs -> partials ->
// restage xd -> finish). 256 blocks x 1024 thr x 100KB LDS = exactly
// 1 block/CU on 256 CUs -> cooperative co-residency holds.
// No registers are live across the grid sync (weights die in phase A;
// src/dst quads load in phase B), so the 64-VGPR/1024-thr cap is safe.
__global__ __launch_bounds__(NTHR) void fused_kernel(
    const float* __restrict__ x,
    const float* __restrict__ W,
    const int* __restrict__ src,
    const int* __restrict__ dst,
    const float* __restrict__ b,
    float* __restrict__ out,
    unsigned int* __restrict__ ws32,
    int n_nodes, int n_pad, int n_quads, int n_edges)
{
    __shared__ __align__(16) unsigned short tab[MAX_TAB32 * 2];
    unsigned int* tab32  = reinterpret_cast<unsigned int*>(tab);
    vi4*          tab128 = reinterpret_cast<vi4*>(tab);

    const int tid = threadIdx.x;

    // ---------------- phase A: node projection ----------------
    {
        __hip_bfloat16* xs = reinterpret_cast<__hip_bfloat16*>(ws32);
        __hip_bfloat16* xd = xs + n_pad;
        const int lane   = tid & 63;
        const int wid    = blockIdx.x * (NTHR / 64) + (tid >> 6);
        const int nwaves = NBLK * (NTHR / 64);
        const int c      = lane & 15;   // 16 lanes per row
        const int r      = lane >> 4;   // 4 rows per wave-iter

        const vf4 wsA = *reinterpret_cast<const vf4*>(W + c * 8);
        const vf4 wsB = *reinterpret_cast<const vf4*>(W + c * 8 + 4);
        const vf4 wdA = *reinterpret_cast<const vf4*>(W + DDIM + c * 8);
        const vf4 wdB = *reinterpret_cast<const vf4*>(W + DDIM + c * 8 + 4);

        const int nq = n_nodes >> 2;
        for (int q = wid; q < nq; q += nwaves) {
            const int row = 4 * q + r;
            const vf4* xp = reinterpret_cast<const vf4*>(
                x + (size_t)row * DDIM + c * 8);
            const vf4 xa = __builtin_nontemporal_load(xp);
            const vf4 xb = __builtin_nontemporal_load(xp + 1);
            float s = xa.x*wsA.x + xa.y*wsA.y + xa.z*wsA.z + xa.w*wsA.w
                    + xb.x*wsB.x + xb.y*wsB.y + xb.z*wsB.z + xb.w*wsB.w;
            float d = xa.x*wdA.x + xa.y*wdA.y + xa.z*wdA.z + xa.w*wdA.w
                    + xb.x*wdB.x + xb.y*wdB.y + xb.z*wdB.z + xb.w*wdB.w;
            #pragma unroll
            for (int m = 8; m >= 1; m >>= 1) {
                s += __shfl_xor(s, m, 64);
                d += __shfl_xor(d, m, 64);
            }
            if (c == 0) {
                xs[row] = __float2bfloat16(s);
                xd[row] = __float2bfloat16(d);
            }
        }
        // tail rows (n_nodes % 4): wave 0, predicated. (empty at 50000)
        const int tail0 = nq << 2;
        if (wid == 0 && tail0 < n_nodes) {
            const int row = tail0 + r;
            float s = 0.f, d = 0.f;
            if (row < n_nodes) {
                const vf4* xp = reinterpret_cast<const vf4*>(
                    x + (size_t)row * DDIM + c * 8);
                const vf4 xa = *xp;
                const vf4 xb = *(xp + 1);
                s = xa.x*wsA.x + xa.y*wsA.y + xa.z*wsA.z + xa.w*wsA.w
                  + xb.x*wsB.x + xb.y*wsB.y + xb.z*wsB.z + xb.w*wsB.w;
                d = xa.x*wdA.x + xa.y*wdA.y + xa.z*wdA.z + xa.w*wdA.w
                  + xb.x*wdB.x + xb.y*wdB.y + xb.z*wdB.z + xb.w*wdB.w;
            }
            #pragma unroll
            for (int m = 8; m >= 1; m >>= 1) {
                s += __shfl_xor(s, m, 64);
                d += __shfl_xor(d, m, 64);
            }
            if (c == 0 && row < n_nodes) {
                xs[row] = __float2bfloat16(s);
                xd[row] = __float2bfloat16(d);
            }
        }
    }

    // device-scope release of the table writes, then grid-wide barrier
    __threadfence();
    cg::this_grid().sync();

    // ---------------- phase B: edge scoring ----------------
    const int gid  = blockIdx.x * NTHR + tid;
    const int T    = NBLK * NTHR;
    const int n32  = (n_nodes + 1) >> 1;   // u32 words per table
    const int n128 = n32 >> 2;             // vi4 words per table
    const unsigned int* xs32 = ws32;
    const unsigned int* xd32 = ws32 + (n_pad >> 1);
    const vi4* xs128 = reinterpret_cast<const vi4*>(xs32);
    const vi4* xd128 = reinterpret_cast<const vi4*>(xd32);

    // issue src/dst index loads early: HBM latency overlaps xs staging
    const int q0 = gid, q1 = gid + T;
    const bool h0 = q0 < n_quads, h1 = q1 < n_quads;
    vi4 s0 = {0,0,0,0}, s1 = {0,0,0,0};
    vi4 t0 = {0,0,0,0}, t1 = {0,0,0,0};
    if (h0) {
        s0 = __builtin_nontemporal_load(reinterpret_cast<const vi4*>(src) + q0);
        t0 = __builtin_nontemporal_load(reinterpret_cast<const vi4*>(dst) + q0);
    }
    if (h1) {
        s1 = __builtin_nontemporal_load(reinterpret_cast<const vi4*>(src) + q1);
        t1 = __builtin_nontemporal_load(reinterpret_cast<const vi4*>(dst) + q1);
    }
    const float bb = b[0];

    // stage xs table (16 B/lane, batched)
    stage_table(tab128, tab32, xs128, xs32, n128, n32, tid);
    __syncthreads();

    // phase 1: partials from xs gathers; dst indices kept in regs
    vf4 p0 = {0,0,0,0}, p1 = {0,0,0,0};
    if (h0) {
        p0.x = bf16_to_f32(tab[s0.x]) + bb;
        p0.y = bf16_to_f32(tab[s0.y]) + bb;
        p0.z = bf16_to_f32(tab[s0.z]) + bb;
        p0.w = bf16_to_f32(tab[s0.w]) + bb;
    }
    if (h1) {
        p1.x = bf16_to_f32(tab[s1.x]) + bb;
        p1.y = bf16_to_f32(tab[s1.y]) + bb;
        p1.z = bf16_to_f32(tab[s1.z]) + bb;
        p1.w = bf16_to_f32(tab[s1.w]) + bb;
    }
    // scalar tail (n_edges % 4)
    const int tail = n_edges & 3;
    int te = -1; float pt = 0.f; int td = 0;
    if (blockIdx.x == 0 && tid < tail) {
        te = (n_quads << 2) + tid;
        td = dst[te];
        pt = bf16_to_f32(tab[src[te]]) + bb;
    }

    // swap table: xd into the same LDS
    __syncthreads();
    stage_table(tab128, tab32, xd128, xd32, n128, n32, tid);
    __syncthreads();

    // phase 2: finish with xd gathers, single store
    if (h0) {
        vf4 o;
        o.x = p0.x + bf16_to_f32(tab[t0.x]);
        o.y = p0.y + bf16_to_f32(tab[t0.y]);
        o.z = p0.z + bf16_to_f32(tab[t0.z]);
        o.w = p0.w + bf16_to_f32(tab[t0.w]);
        __builtin_nontemporal_store(o, reinterpret_cast<vf4*>(out) + q0);
    }
    if (h1) {
        vf4 o;
        o.x = p1.x + bf16_to_f32(tab[t1.x]);
        o.y = p1.y + bf16_to_f32(tab[t1.y]);
        o.z = p1.z + bf16_to_f32(tab[t1.z]);
        o.w = p1.w + bf16_to_f32(tab[t1.w]);
        __builtin_nontemporal_store(o, reinterpret_cast<vf4*>(out) + q1);
    }
    if (te >= 0) out[te] = pt + bf16_to_f32(tab[td]);
}

extern "C" void kernel_launch(void* const* d_in, const int* in_sizes, int n_in,
                              void* d_out, int out_size, void* d_ws, size_t ws_size,
                              hipStream_t stream) {
    const float* x   = (const float*)d_in[0];
    const int*   src = (const int*)d_in[1];
    const int*   dst = (const int*)d_in[2];
    const float* W   = (const float*)d_in[3];
    const float* b   = (const float*)d_in[4];
    float* out = (float*)d_out;

    int n_nodes = in_sizes[0] / DDIM;
    int n_edges = in_sizes[1];
    int n_pad   = (n_nodes + 7) & ~7;   // xd table 16B-aligned
    int n_quads = n_edges >> 2;
    unsigned int* ws32 = (unsigned int*)d_ws;

    void* args[] = {
        (void*)&x, (void*)&W, (void*)&src, (void*)&dst, (void*)&b,
        (void*)&out, (void*)&ws32,
        (void*)&n_nodes, (void*)&n_pad, (void*)&n_quads, (void*)&n_edges
    };
    hipLaunchCooperativeKernel((const void*)fused_kernel,
                               dim3(NBLK), dim3(NTHR), args, 0, stream);
}

// Round 4
// 19.627 us; speedup vs baseline: 7.1202x; 7.1202x over previous
//
#include <hip/hip_runtime.h>
#include <hip/hip_bf16.h>

#define DDIM 128
#define K2_BLOCKS 256
#define K2_THREADS 1024
#define MAX_TAB32 25088   // 50176 bf16 entries = 100352 B LDS (xs only)

typedef float vf4 __attribute__((ext_vector_type(4)));
typedef int   vi4 __attribute__((ext_vector_type(4)));

__device__ __forceinline__ float bf16_to_f32(unsigned short u) {
    return __uint_as_float(((unsigned int)u) << 16);
}

// Grid-stride node projection: one wave covers 4 rows per iteration.
// c = lane&15 covers dims [8c, 8c+7] (two float4), r = lane>>4 selects the
// row of the quad. 4-level shfl reduce (2 shuffles/row). Results stored as
// bf16 tables for k2.
__global__ __launch_bounds__(256) void node_proj_kernel(
    const float* __restrict__ x,
    const float* __restrict__ W,
    __hip_bfloat16* __restrict__ xs,
    __hip_bfloat16* __restrict__ xd,
    int n_nodes)
{
    const int tib    = threadIdx.x;
    const int lane   = tib & 63;
    const int wid    = blockIdx.x * (256 / 64) + (tib >> 6);
    const int nwaves = gridDim.x * (256 / 64);
    const int c      = lane & 15;   // 16 lanes per row
    const int r      = lane >> 4;   // 4 rows per wave-iter

    const vf4 wsA = *reinterpret_cast<const vf4*>(W + c * 8);
    const vf4 wsB = *reinterpret_cast<const vf4*>(W + c * 8 + 4);
    const vf4 wdA = *reinterpret_cast<const vf4*>(W + DDIM + c * 8);
    const vf4 wdB = *reinterpret_cast<const vf4*>(W + DDIM + c * 8 + 4);

    const int nq = n_nodes >> 2;
    for (int q = wid; q < nq; q += nwaves) {
        const int row = 4 * q + r;
        const vf4* xp = reinterpret_cast<const vf4*>(x + (size_t)row * DDIM + c * 8);
        const vf4 xa = __builtin_nontemporal_load(xp);
        const vf4 xb = __builtin_nontemporal_load(xp + 1);
        float s = xa.x*wsA.x + xa.y*wsA.y + xa.z*wsA.z + xa.w*wsA.w
                + xb.x*wsB.x + xb.y*wsB.y + xb.z*wsB.z + xb.w*wsB.w;
        float d = xa.x*wdA.x + xa.y*wdA.y + xa.z*wdA.z + xa.w*wdA.w
                + xb.x*wdB.x + xb.y*wdB.y + xb.z*wdB.z + xb.w*wdB.w;
        #pragma unroll
        for (int m = 8; m >= 1; m >>= 1) {
            s += __shfl_xor(s, m, 64);
            d += __shfl_xor(d, m, 64);
        }
        if (c == 0) {
            xs[row] = __float2bfloat16(s);
            xd[row] = __float2bfloat16(d);
        }
    }
    // tail rows (n_nodes % 4): wave 0, predicated. (empty at 50000)
    const int tail0 = nq << 2;
    if (wid == 0 && tail0 < n_nodes) {
        const int row = tail0 + r;
        float s = 0.f, d = 0.f;
        if (row < n_nodes) {
            const vf4* xp = reinterpret_cast<const vf4*>(x + (size_t)row * DDIM + c * 8);
            const vf4 xa = *xp;
            const vf4 xb = *(xp + 1);
            s = xa.x*wsA.x + xa.y*wsA.y + xa.z*wsA.z + xa.w*wsA.w
              + xb.x*wsB.x + xb.y*wsB.y + xb.z*wsB.z + xb.w*wsB.w;
            d = xa.x*wdA.x + xa.y*wdA.y + xa.z*wdA.z + xa.w*wdA.w
              + xb.x*wdB.x + xb.y*wdB.y + xb.z*wdB.z + xb.w*wdB.w;
        }
        #pragma unroll
        for (int m = 8; m >= 1; m >>= 1) {
            s += __shfl_xor(s, m, 64);
            d += __shfl_xor(d, m, 64);
        }
        if (c == 0 && row < n_nodes) {
            xs[row] = __float2bfloat16(s);
            xd[row] = __float2bfloat16(d);
        }
    }
}

// Batched vi4 copy: 4 loads in flight, then 4 LDS stores. Transient
// register cost = 16 VGPRs; never held across a barrier.
__device__ __forceinline__ void stage_table(
    vi4* __restrict__ tab128, unsigned int* __restrict__ tab32,
    const vi4* __restrict__ g128, const unsigned int* __restrict__ g32,
    int n128, int n32, int tid)
{
    int i = tid;
    for (; i + 3 * K2_THREADS < n128; i += 4 * K2_THREADS) {
        const vi4 a = g128[i];
        const vi4 b = g128[i +     K2_THREADS];
        const vi4 c = g128[i + 2 * K2_THREADS];
        const vi4 d = g128[i + 3 * K2_THREADS];
        tab128[i                 ] = a;
        tab128[i +     K2_THREADS] = b;
        tab128[i + 2 * K2_THREADS] = c;
        tab128[i + 3 * K2_THREADS] = d;
    }
    for (; i < n128; i += K2_THREADS) tab128[i] = g128[i];
    for (int j = (n128 << 2) + tid; j < n32; j += K2_THREADS) tab32[j] = g32[j];
}

// Hybrid edge scorer, single barrier:
//   - xs table staged once into LDS (L2-BW copy, overlaps src/dst HBM fetch)
//   - xd gathered DIRECTLY from global memory (100 KB table is L2-resident,
//     ~32x reuse per node; plain cached loads, NOT nontemporal)
// The two gather streams use different pipes (DS vs TA/L2) and overlap.
// vs. the two-stage swap: saves 256x100KB of L2/L3 staging traffic, one
// exposed stage phase, and two barriers.
__global__ __launch_bounds__(K2_THREADS) void edge_hybrid_kernel(
    const int* __restrict__ src,
    const int* __restrict__ dst,
    const unsigned int* __restrict__ xs32,
    const unsigned short* __restrict__ xd16,
    const float* __restrict__ b,
    float* __restrict__ out,
    int n_nodes, int n_quads, int n_edges)
{
    __shared__ __align__(16) unsigned short tab[MAX_TAB32 * 2];
    unsigned int* tab32  = reinterpret_cast<unsigned int*>(tab);
    vi4*          tab128 = reinterpret_cast<vi4*>(tab);

    const int tid  = threadIdx.x;
    const int gid  = blockIdx.x * K2_THREADS + tid;
    const int T    = K2_BLOCKS * K2_THREADS;
    const int n32  = (n_nodes + 1) >> 1;   // u32 words in xs table
    const int n128 = n32 >> 2;             // vi4 words in xs table
    const vi4* xs128 = reinterpret_cast<const vi4*>(xs32);

    // ---- issue src/dst index loads first: HBM latency overlaps staging ----
    const int q0 = gid, q1 = gid + T;
    const bool h0 = q0 < n_quads, h1 = q1 < n_quads;
    vi4 s0 = {0,0,0,0}, s1 = {0,0,0,0};
    vi4 t0 = {0,0,0,0}, t1 = {0,0,0,0};
    if (h0) {
        s0 = __builtin_nontemporal_load(reinterpret_cast<const vi4*>(src) + q0);
        t0 = __builtin_nontemporal_load(reinterpret_cast<const vi4*>(dst) + q0);
    }
    if (h1) {
        s1 = __builtin_nontemporal_load(reinterpret_cast<const vi4*>(src) + q1);
        t1 = __builtin_nontemporal_load(reinterpret_cast<const vi4*>(dst) + q1);
    }
    const float bb = b[0];

    // ---- stage xs into LDS (16 B/lane, batched; pure L2 traffic) ----
    stage_table(tab128, tab32, xs128, xs32, n128, n32, tid);

    // ---- issue xd gathers from global (L2-resident, cached loads).
    //      Latency hides under the barrier wait below. ----
    float g0x=0.f,g0y=0.f,g0z=0.f,g0w=0.f, g1x=0.f,g1y=0.f,g1z=0.f,g1w=0.f;
    if (h0) {
        g0x = bf16_to_f32(xd16[t0.x]);
        g0y = bf16_to_f32(xd16[t0.y]);
        g0z = bf16_to_f32(xd16[t0.z]);
        g0w = bf16_to_f32(xd16[t0.w]);
    }
    if (h1) {
        g1x = bf16_to_f32(xd16[t1.x]);
        g1y = bf16_to_f32(xd16[t1.y]);
        g1z = bf16_to_f32(xd16[t1.z]);
        g1w = bf16_to_f32(xd16[t1.w]);
    }
    // scalar tail (n_edges % 4): indices + xd gather before the barrier too
    const int tail = n_edges & 3;
    int te = -1; float gt = 0.f; int ts = 0;
    if (blockIdx.x == 0 && tid < tail) {
        te = (n_quads << 2) + tid;
        ts = src[te];
        gt = bf16_to_f32(xd16[dst[te]]);
    }

    __syncthreads();

    // ---- xs LDS gathers + combine + single store ----
    if (h0) {
        vf4 o;
        o.x = bf16_to_f32(tab[s0.x]) + g0x + bb;
        o.y = bf16_to_f32(tab[s0.y]) + g0y + bb;
        o.z = bf16_to_f32(tab[s0.z]) + g0z + bb;
        o.w = bf16_to_f32(tab[s0.w]) + g0w + bb;
        __builtin_nontemporal_store(o, reinterpret_cast<vf4*>(out) + q0);
    }
    if (h1) {
        vf4 o;
        o.x = bf16_to_f32(tab[s1.x]) + g1x + bb;
        o.y = bf16_to_f32(tab[s1.y]) + g1y + bb;
        o.z = bf16_to_f32(tab[s1.z]) + g1z + bb;
        o.w = bf16_to_f32(tab[s1.w]) + g1w + bb;
        __builtin_nontemporal_store(o, reinterpret_cast<vf4*>(out) + q1);
    }
    if (te >= 0) out[te] = bf16_to_f32(tab[ts]) + gt + bb;
}

extern "C" void kernel_launch(void* const* d_in, const int* in_sizes, int n_in,
                              void* d_out, int out_size, void* d_ws, size_t ws_size,
                              hipStream_t stream) {
    const float* x   = (const float*)d_in[0];
    const int*   src = (const int*)d_in[1];
    const int*   dst = (const int*)d_in[2];
    const float* W   = (const float*)d_in[3];
    const float* b   = (const float*)d_in[4];
    float* out = (float*)d_out;

    const int n_nodes = in_sizes[0] / DDIM;
    const int n_edges = in_sizes[1];

    __hip_bfloat16* xs = (__hip_bfloat16*)d_ws;
    // pad xd so the xd table starts 16B-aligned
    const int n_pad = (n_nodes + 7) & ~7;
    __hip_bfloat16* xd = xs + n_pad;

    // K1: 4-rows-per-wave projection.
    node_proj_kernel<<<2048, 256, 0, stream>>>(x, W, xs, xd, n_nodes);

    // K2: hybrid LDS(xs) + L2(xd) edge scorer, single barrier.
    const int n_quads = n_edges >> 2;
    edge_hybrid_kernel<<<K2_BLOCKS, K2_THREADS, 0, stream>>>(
        src, dst, (const unsigned int*)xs, (const unsigned short*)xd, b, out,
        n_nodes, n_quads, n_edges);
}

// Round 5
// 17.243 us; speedup vs baseline: 8.1042x; 1.1382x over previous
//
#include <hip/hip_runtime.h>
#include <hip/hip_bf16.h>

#define DDIM 128
#define K2_BLOCKS 256
#define K2_THREADS 1024
#define MAX_TAB32 25088   // 50176 bf16 entries = 100352 B LDS

typedef float vf4 __attribute__((ext_vector_type(4)));
typedef int   vi4 __attribute__((ext_vector_type(4)));

__device__ __forceinline__ float bf16_to_f32(unsigned short u) {
    return __uint_as_float(((unsigned int)u) << 16);
}

// Exact-cover node projection: one wave handles exactly ONE quad of rows
// (no grid-stride loop). c = lane&15 covers dims [8c, 8c+7], r = lane>>4
// selects the row. Launch ceil(nq/4) blocks of 256; the HW scheduler
// backfills CUs as blocks retire -> near-perfect load balance vs the old
// 1.53-iters/wave static partition whose 2nd iteration drained at ~half
// concurrency.
__global__ __launch_bounds__(256) void node_proj_kernel(
    const float* __restrict__ x,
    const float* __restrict__ W,
    __hip_bfloat16* __restrict__ xs,
    __hip_bfloat16* __restrict__ xd,
    int n_nodes)
{
    const int tib  = threadIdx.x;
    const int lane = tib & 63;
    const int q    = blockIdx.x * (256 / 64) + (tib >> 6);   // quad index
    const int c    = lane & 15;   // 16 lanes per row
    const int r    = lane >> 4;   // 4 rows per quad

    const vf4 wsA = *reinterpret_cast<const vf4*>(W + c * 8);
    const vf4 wsB = *reinterpret_cast<const vf4*>(W + c * 8 + 4);
    const vf4 wdA = *reinterpret_cast<const vf4*>(W + DDIM + c * 8);
    const vf4 wdB = *reinterpret_cast<const vf4*>(W + DDIM + c * 8 + 4);

    const int nq = n_nodes >> 2;
    if (q < nq) {
        const int row = 4 * q + r;
        const vf4* xp = reinterpret_cast<const vf4*>(x + (size_t)row * DDIM + c * 8);
        const vf4 xa = __builtin_nontemporal_load(xp);
        const vf4 xb = __builtin_nontemporal_load(xp + 1);
        float s = xa.x*wsA.x + xa.y*wsA.y + xa.z*wsA.z + xa.w*wsA.w
                + xb.x*wsB.x + xb.y*wsB.y + xb.z*wsB.z + xb.w*wsB.w;
        float d = xa.x*wdA.x + xa.y*wdA.y + xa.z*wdA.z + xa.w*wdA.w
                + xb.x*wdB.x + xb.y*wdB.y + xb.z*wdB.z + xb.w*wdB.w;
        #pragma unroll
        for (int m = 8; m >= 1; m >>= 1) {
            s += __shfl_xor(s, m, 64);
            d += __shfl_xor(d, m, 64);
        }
        if (c == 0) {
            xs[row] = __float2bfloat16(s);
            xd[row] = __float2bfloat16(d);
        }
    }
    // tail rows (n_nodes % 4): first wave of block 0, predicated.
    // (empty at n_nodes = 50000)
    const int tail0 = nq << 2;
    if (blockIdx.x == 0 && (tib >> 6) == 0 && tail0 < n_nodes) {
        const int row = tail0 + r;
        float s = 0.f, d = 0.f;
        if (row < n_nodes) {
            const vf4* xp = reinterpret_cast<const vf4*>(x + (size_t)row * DDIM + c * 8);
            const vf4 xa = *xp;
            const vf4 xb = *(xp + 1);
            s = xa.x*wsA.x + xa.y*wsA.y + xa.z*wsA.z + xa.w*wsA.w
              + xb.x*wsB.x + xb.y*wsB.y + xb.z*wsB.z + xb.w*wsB.w;
            d = xa.x*wdA.x + xa.y*wdA.y + xa.z*wdA.z + xa.w*wdA.w
              + xb.x*wdB.x + xb.y*wdB.y + xb.z*wdB.z + xb.w*wdB.w;
        }
        #pragma unroll
        for (int m = 8; m >= 1; m >>= 1) {
            s += __shfl_xor(s, m, 64);
            d += __shfl_xor(d, m, 64);
        }
        if (c == 0 && row < n_nodes) {
            xs[row] = __float2bfloat16(s);
            xd[row] = __float2bfloat16(d);
        }
    }
}

// Batched vi4 copy: 4 loads in flight, then 4 LDS stores. Transient
// register cost = 16 VGPRs; never held across a barrier.
__device__ __forceinline__ void stage_table(
    vi4* __restrict__ tab128, unsigned int* __restrict__ tab32,
    const vi4* __restrict__ g128, const unsigned int* __restrict__ g32,
    int n128, int n32, int tid)
{
    int i = tid;
    for (; i + 3 * K2_THREADS < n128; i += 4 * K2_THREADS) {
        const vi4 a = g128[i];
        const vi4 b = g128[i +     K2_THREADS];
        const vi4 c = g128[i + 2 * K2_THREADS];
        const vi4 d = g128[i + 3 * K2_THREADS];
        tab128[i                 ] = a;
        tab128[i +     K2_THREADS] = b;
        tab128[i + 2 * K2_THREADS] = c;
        tab128[i + 3 * K2_THREADS] = d;
    }
    for (; i < n128; i += K2_THREADS) tab128[i] = g128[i];
    for (int j = (n128 << 2) + tid; j < n32; j += K2_THREADS) tab32[j] = g32[j];
}

// Edge scores with LDS-resident tables. Swap structure (stage xs ->
// partials -> restage xd -> finish). Only the src/dst index quads are
// issued early / held in registers (16 VGPRs) -- table data streams
// global->LDS through a small transient register window. Proven: LDS
// gathers beat direct L2 gathers ~4x for this random-index pattern
// (round-4 hybrid regression).
__global__ __launch_bounds__(K2_THREADS) void edge_lds_kernel(
    const int* __restrict__ src,
    const int* __restrict__ dst,
    const unsigned int* __restrict__ xs32,
    const unsigned int* __restrict__ xd32,
    const float* __restrict__ b,
    float* __restrict__ out,
    int n_nodes, int n_quads, int n_edges)
{
    __shared__ __align__(16) unsigned short tab[MAX_TAB32 * 2];
    unsigned int* tab32  = reinterpret_cast<unsigned int*>(tab);
    vi4*          tab128 = reinterpret_cast<vi4*>(tab);

    const int tid  = threadIdx.x;
    const int gid  = blockIdx.x * K2_THREADS + tid;
    const int T    = K2_BLOCKS * K2_THREADS;
    const int n32  = (n_nodes + 1) >> 1;   // u32 words per table
    const int n128 = n32 >> 2;             // vi4 words per table
    const vi4* xs128 = reinterpret_cast<const vi4*>(xs32);
    const vi4* xd128 = reinterpret_cast<const vi4*>(xd32);

    // ---- issue src/dst index loads early: HBM latency overlaps staging ----
    const int q0 = gid, q1 = gid + T;
    const bool h0 = q0 < n_quads, h1 = q1 < n_quads;
    vi4 s0 = {0,0,0,0}, s1 = {0,0,0,0};
    vi4 t0 = {0,0,0,0}, t1 = {0,0,0,0};
    if (h0) {
        s0 = __builtin_nontemporal_load(reinterpret_cast<const vi4*>(src) + q0);
        t0 = __builtin_nontemporal_load(reinterpret_cast<const vi4*>(dst) + q0);
    }
    if (h1) {
        s1 = __builtin_nontemporal_load(reinterpret_cast<const vi4*>(src) + q1);
        t1 = __builtin_nontemporal_load(reinterpret_cast<const vi4*>(dst) + q1);
    }
    const float bb = b[0];

    // ---- stage xs table (16 B/lane, batched) ----
    stage_table(tab128, tab32, xs128, xs32, n128, n32, tid);
    __syncthreads();

    // ---- phase 1: partials from xs gathers; dst indices kept in regs ----
    vf4 p0 = {0,0,0,0}, p1 = {0,0,0,0};
    if (h0) {
        p0.x = bf16_to_f32(tab[s0.x]) + bb;
        p0.y = bf16_to_f32(tab[s0.y]) + bb;
        p0.z = bf16_to_f32(tab[s0.z]) + bb;
        p0.w = bf16_to_f32(tab[s0.w]) + bb;
    }
    if (h1) {
        p1.x = bf16_to_f32(tab[s1.x]) + bb;
        p1.y = bf16_to_f32(tab[s1.y]) + bb;
        p1.z = bf16_to_f32(tab[s1.z]) + bb;
        p1.w = bf16_to_f32(tab[s1.w]) + bb;
    }
    // scalar tail (n_edges % 4)
    const int tail = n_edges & 3;
    int te = -1; float pt = 0.f; int td = 0;
    if (blockIdx.x == 0 && tid < tail) {
        te = (n_quads << 2) + tid;
        td = dst[te];
        pt = bf16_to_f32(tab[src[te]]) + bb;
    }

    // ---- swap table: xd into the same LDS ----
    __syncthreads();
    stage_table(tab128, tab32, xd128, xd32, n128, n32, tid);
    __syncthreads();

    // ---- phase 2: finish with xd gathers, single store ----
    if (h0) {
        vf4 o;
        o.x = p0.x + bf16_to_f32(tab[t0.x]);
        o.y = p0.y + bf16_to_f32(tab[t0.y]);
        o.z = p0.z + bf16_to_f32(tab[t0.z]);
        o.w = p0.w + bf16_to_f32(tab[t0.w]);
        __builtin_nontemporal_store(o, reinterpret_cast<vf4*>(out) + q0);
    }
    if (h1) {
        vf4 o;
        o.x = p1.x + bf16_to_f32(tab[t1.x]);
        o.y = p1.y + bf16_to_f32(tab[t1.y]);
        o.z = p1.z + bf16_to_f32(tab[t1.z]);
        o.w = p1.w + bf16_to_f32(tab[t1.w]);
        __builtin_nontemporal_store(o, reinterpret_cast<vf4*>(out) + q1);
    }
    if (te >= 0) out[te] = pt + bf16_to_f32(tab[td]);
}

extern "C" void kernel_launch(void* const* d_in, const int* in_sizes, int n_in,
                              void* d_out, int out_size, void* d_ws, size_t ws_size,
                              hipStream_t stream) {
    const float* x   = (const float*)d_in[0];
    const int*   src = (const int*)d_in[1];
    const int*   dst = (const int*)d_in[2];
    const float* W   = (const float*)d_in[3];
    const float* b   = (const float*)d_in[4];
    float* out = (float*)d_out;

    const int n_nodes = in_sizes[0] / DDIM;
    const int n_edges = in_sizes[1];

    __hip_bfloat16* xs = (__hip_bfloat16*)d_ws;
    // pad xd so the xd table starts 16B-aligned for vi4 staging
    const int n_pad = (n_nodes + 7) & ~7;
    __hip_bfloat16* xd = xs + n_pad;

    // K1: exact-cover projection, one quad per wave.
    const int nq = n_nodes >> 2;
    int k1_blocks = (nq + 3) >> 2;           // 4 quads (waves) per block
    if (k1_blocks < 1) k1_blocks = 1;
    node_proj_kernel<<<k1_blocks, 256, 0, stream>>>(x, W, xs, xd, n_nodes);

    // K2: LDS-table edge scorer, fixed 256 x 1024 grid (<= 2 quads/thread).
    const int n_quads = n_edges >> 2;
    edge_lds_kernel<<<K2_BLOCKS, K2_THREADS, 0, stream>>>(
        src, dst, (const unsigned int*)xs, (const unsigned int*)xd, b, out,
        n_nodes, n_quads, n_edges);
}

// Round 6
// 16.850 us; speedup vs baseline: 8.2935x; 1.0234x over previous
//
#include <hip/hip_runtime.h>
#include <hip/hip_bf16.h>

#define DDIM 128
#define K2_BLOCKS 256
#define K2_THREADS 1024
#define MAX_TAB32 25088   // 50176 bf16 entries = 100352 B LDS = 98 KB DMA units

typedef float vf4 __attribute__((ext_vector_type(4)));
typedef int   vi4 __attribute__((ext_vector_type(4)));

__device__ __forceinline__ float bf16_to_f32(unsigned short u) {
    return __uint_as_float(((unsigned int)u) << 16);
}

// Async global->LDS DMA, 16 B per lane (1 KB per wave-issue). LDS dest is
// wave-uniform base + lane*16 (HW rule); our staging is linear so this is
// the exact match. Size must be a literal 16.
__device__ __forceinline__ void lds_dma16(const void* g, void* l) {
    __builtin_amdgcn_global_load_lds(
        (const __attribute__((address_space(1))) unsigned int*)g,
        (__attribute__((address_space(3))) unsigned int*)l,
        16, 0, 0);
}

// Node projection: one wave covers EIGHT rows (two quads). c = lane&15
// covers dims [8c, 8c+7]; r = lane>>4 picks the row within each quad.
// 4 x 16B loads in flight per lane (2x the old scheme) and 4 interleaved
// shuffle-reduce chains (4-way ILP on the ds-swizzle latency). Predicated
// row guards subsume all tails.
__global__ __launch_bounds__(256) void node_proj_kernel(
    const float* __restrict__ x,
    const float* __restrict__ W,
    __hip_bfloat16* __restrict__ xs,
    __hip_bfloat16* __restrict__ xd,
    int n_nodes)
{
    const int tib  = threadIdx.x;
    const int lane = tib & 63;
    const int w    = blockIdx.x * 4 + (tib >> 6);   // wave id, 8 rows each
    const int c    = lane & 15;   // 16 lanes per row
    const int r    = lane >> 4;   // row within quad

    const vf4 wsA = *reinterpret_cast<const vf4*>(W + c * 8);
    const vf4 wsB = *reinterpret_cast<const vf4*>(W + c * 8 + 4);
    const vf4 wdA = *reinterpret_cast<const vf4*>(W + DDIM + c * 8);
    const vf4 wdB = *reinterpret_cast<const vf4*>(W + DDIM + c * 8 + 4);

    const int ra = 8 * w + r;       // rows of quad A
    const int rb = ra + 4;          // rows of quad B
    vf4 a0 = {0,0,0,0}, a1 = {0,0,0,0};
    vf4 b0 = {0,0,0,0}, b1 = {0,0,0,0};
    if (ra < n_nodes) {
        const vf4* pa = reinterpret_cast<const vf4*>(x + (size_t)ra * DDIM + c * 8);
        a0 = __builtin_nontemporal_load(pa);
        a1 = __builtin_nontemporal_load(pa + 1);
    }
    if (rb < n_nodes) {
        const vf4* pb = reinterpret_cast<const vf4*>(x + (size_t)rb * DDIM + c * 8);
        b0 = __builtin_nontemporal_load(pb);
        b1 = __builtin_nontemporal_load(pb + 1);
    }

    float sA = a0.x*wsA.x + a0.y*wsA.y + a0.z*wsA.z + a0.w*wsA.w
             + a1.x*wsB.x + a1.y*wsB.y + a1.z*wsB.z + a1.w*wsB.w;
    float dA = a0.x*wdA.x + a0.y*wdA.y + a0.z*wdA.z + a0.w*wdA.w
             + a1.x*wdB.x + a1.y*wdB.y + a1.z*wdB.z + a1.w*wdB.w;
    float sB = b0.x*wsA.x + b0.y*wsA.y + b0.z*wsA.z + b0.w*wsA.w
             + b1.x*wsB.x + b1.y*wsB.y + b1.z*wsB.z + b1.w*wsB.w;
    float dB = b0.x*wdA.x + b0.y*wdA.y + b0.z*wdA.z + b0.w*wdA.w
             + b1.x*wdB.x + b1.y*wdB.y + b1.z*wdB.z + b1.w*wdB.w;

    #pragma unroll
    for (int m = 8; m >= 1; m >>= 1) {
        sA += __shfl_xor(sA, m, 64);
        dA += __shfl_xor(dA, m, 64);
        sB += __shfl_xor(sB, m, 64);
        dB += __shfl_xor(dB, m, 64);
    }
    if (c == 0) {
        if (ra < n_nodes) {
            xs[ra] = __float2bfloat16(sA);
            xd[ra] = __float2bfloat16(dA);
        }
        if (rb < n_nodes) {
            xs[rb] = __float2bfloat16(sB);
            xd[rb] = __float2bfloat16(dB);
        }
    }
}

// Edge scores with LDS-resident tables. Swap structure (stage xs ->
// partials -> restage xd -> finish), but staging is now pure async DMA
// (global_load_lds x16B): no VGPR round-trip, no staging VALU. Tables are
// laid out in 1KB DMA units in the workspace; each wave issues <=7 DMA ops
// per table and __syncthreads() drains them. LDS gathers proven ~4x
// cheaper than direct L2 gathers for this random pattern (round 4).
__global__ __launch_bounds__(K2_THREADS) void edge_lds_kernel(
    const int* __restrict__ src,
    const int* __restrict__ dst,
    const unsigned char* __restrict__ xs_b,   // table base, nb KB
    const unsigned char* __restrict__ xd_b,   // table base, nb KB
    const float* __restrict__ b,
    float* __restrict__ out,
    int nb, int n_quads, int n_edges)
{
    __shared__ __align__(16) unsigned short tab[MAX_TAB32 * 2];
    unsigned char* tabb = reinterpret_cast<unsigned char*>(tab);

    const int tid = threadIdx.x;
    const int wv  = tid >> 6;     // wave in block (0..15)
    const int ln  = tid & 63;
    const int gid = blockIdx.x * K2_THREADS + tid;
    const int T   = K2_BLOCKS * K2_THREADS;

    // ---- issue src/dst index loads first: HBM latency overlaps staging ----
    const int q0 = gid, q1 = gid + T;
    const bool h0 = q0 < n_quads, h1 = q1 < n_quads;
    vi4 s0 = {0,0,0,0}, s1 = {0,0,0,0};
    vi4 t0 = {0,0,0,0}, t1 = {0,0,0,0};
    if (h0) {
        s0 = __builtin_nontemporal_load(reinterpret_cast<const vi4*>(src) + q0);
        t0 = __builtin_nontemporal_load(reinterpret_cast<const vi4*>(dst) + q0);
    }
    if (h1) {
        s1 = __builtin_nontemporal_load(reinterpret_cast<const vi4*>(src) + q1);
        t1 = __builtin_nontemporal_load(reinterpret_cast<const vi4*>(dst) + q1);
    }
    const float bb = b[0];

    // ---- stage xs table: async DMA, 1 KB per wave-issue ----
    for (int i = wv; i < nb; i += K2_THREADS / 64)
        lds_dma16(xs_b + (size_t)i * 1024 + ln * 16, tabb + i * 1024);
    __syncthreads();   // drains vmcnt(0): DMA + src/dst loads complete

    // ---- phase 1: partials from xs gathers; dst indices kept in regs ----
    vf4 p0 = {0,0,0,0}, p1 = {0,0,0,0};
    if (h0) {
        p0.x = bf16_to_f32(tab[s0.x]) + bb;
        p0.y = bf16_to_f32(tab[s0.y]) + bb;
        p0.z = bf16_to_f32(tab[s0.z]) + bb;
        p0.w = bf16_to_f32(tab[s0.w]) + bb;
    }
    if (h1) {
        p1.x = bf16_to_f32(tab[s1.x]) + bb;
        p1.y = bf16_to_f32(tab[s1.y]) + bb;
        p1.z = bf16_to_f32(tab[s1.z]) + bb;
        p1.w = bf16_to_f32(tab[s1.w]) + bb;
    }
    // scalar tail (n_edges % 4)
    const int tail = n_edges & 3;
    int te = -1; float pt = 0.f; int td = 0;
    if (blockIdx.x == 0 && tid < tail) {
        te = (n_quads << 2) + tid;
        td = dst[te];
        pt = bf16_to_f32(tab[reinterpret_cast<const unsigned short*>(xs_b)[0] == 0
                             ? src[te] : src[te]]) + bb;  // plain gather
    }

    // ---- swap table: xd via async DMA into the same LDS ----
    __syncthreads();   // all waves done reading xs
    for (int i = wv; i < nb; i += K2_THREADS / 64)
        lds_dma16(xd_b + (size_t)i * 1024 + ln * 16, tabb + i * 1024);
    __syncthreads();   // drains DMA

    // ---- phase 2: finish with xd gathers, single store ----
    if (h0) {
        vf4 o;
        o.x = p0.x + bf16_to_f32(tab[t0.x]);
        o.y = p0.y + bf16_to_f32(tab[t0.y]);
        o.z = p0.z + bf16_to_f32(tab[t0.z]);
        o.w = p0.w + bf16_to_f32(tab[t0.w]);
        __builtin_nontemporal_store(o, reinterpret_cast<vf4*>(out) + q0);
    }
    if (h1) {
        vf4 o;
        o.x = p1.x + bf16_to_f32(tab[t1.x]);
        o.y = p1.y + bf16_to_f32(tab[t1.y]);
        o.z = p1.z + bf16_to_f32(tab[t1.z]);
        o.w = p1.w + bf16_to_f32(tab[t1.w]);
        __builtin_nontemporal_store(o, reinterpret_cast<vf4*>(out) + q1);
    }
    if (te >= 0) out[te] = pt + bf16_to_f32(tab[td]);
}

extern "C" void kernel_launch(void* const* d_in, const int* in_sizes, int n_in,
                              void* d_out, int out_size, void* d_ws, size_t ws_size,
                              hipStream_t stream) {
    const float* x   = (const float*)d_in[0];
    const int*   src = (const int*)d_in[1];
    const int*   dst = (const int*)d_in[2];
    const float* W   = (const float*)d_in[3];
    const float* b   = (const float*)d_in[4];
    float* out = (float*)d_out;

    const int n_nodes = in_sizes[0] / DDIM;
    const int n_edges = in_sizes[1];

    // table layout in 1 KB DMA units: xs at [0, nb KB), xd at [nb, 2*nb KB)
    const int n32 = (n_nodes + 1) >> 1;
    const int nb  = (n32 * 4 + 1023) >> 10;          // KB units per table
    unsigned char* wsb = (unsigned char*)d_ws;
    __hip_bfloat16* xs = (__hip_bfloat16*)wsb;
    __hip_bfloat16* xd = (__hip_bfloat16*)(wsb + (size_t)nb * 1024);

    // K1: 8-rows-per-wave projection, exact cover (32 rows/block).
    const int k1_blocks = (n_nodes + 31) >> 5;
    node_proj_kernel<<<k1_blocks, 256, 0, stream>>>(x, W, xs, xd, n_nodes);

    // K2: LDS-table edge scorer with async-DMA staging.
    const int n_quads = n_edges >> 2;
    edge_lds_kernel<<<K2_BLOCKS, K2_THREADS, 0, stream>>>(
        src, dst, wsb, wsb + (size_t)nb * 1024, b, out,
        nb, n_quads, n_edges);
}